// Round 1
// baseline (131.305 us; speedup 1.0000x reference)
//
#include <hip/hip_runtime.h>
#include <hip/hip_bf16.h>
#include <stdint.h>

#define HW 192
#define NC 128
#define NP 64
#define NG 64
#define TILE_BYTES (HW * NC * 2)   /* 49152 B per bf16 tile */
#define KEPS 1e-5f

typedef __attribute__((ext_vector_type(8))) short short8;
typedef __attribute__((ext_vector_type(4))) float f32x4;

// ---------------------------------------------------------------------------
// Prep: f32 [n][C][HW] -> bf16 transposed [n][HW][C], XOR-swizzled within each
// 256-byte row: byte col = (2c) ^ ((hw&7)<<4). GEMM kernel then stages LINEAR
// (global_load_lds) and ds_reads with the same XOR -> conflict-free.
// ---------------------------------------------------------------------------
__global__ void prep_kernel(const float* __restrict__ prob,
                            const float* __restrict__ gal,
                            unsigned short* __restrict__ probT,
                            unsigned short* __restrict__ galT) {
  int b = blockIdx.x;            // 512 blocks: 128 slices x 4 quarters
  int slice = b >> 2;
  int part = b & 3;
  const float* src;
  unsigned short* dst;
  if (slice < NP) { src = prob + (size_t)slice * NC * HW; dst = probT + (size_t)slice * HW * NC; }
  else            { src = gal + (size_t)(slice - NP) * NC * HW; dst = galT + (size_t)(slice - NP) * HW * NC; }
  int begin = part * (NC * HW / 4);
  int end = begin + (NC * HW / 4);
  for (int idx = begin + threadIdx.x; idx < end; idx += blockDim.x) {
    int hw = idx >> 7;           // 0..191
    int c = idx & 127;
    float v = src[c * HW + hw];
    __hip_bfloat16 h = __float2bfloat16(v);
    unsigned short bits = __builtin_bit_cast(unsigned short, h);
    int cb = (2 * c) ^ ((hw & 7) << 4);
    dst[hw * NC + (cb >> 1)] = bits;
  }
}

// ---------------------------------------------------------------------------
// Pair kernel: 256 blocks (g, probe-chunk-of-16). LDS: gal tile + 2x probe
// tile (double buffered) + reduction scratch = 150560 B -> 1 block/CU.
// ---------------------------------------------------------------------------
extern __shared__ char smem[];

__device__ __forceinline__ void gl_lds16(const void* gsrc, void* ldst) {
  __builtin_amdgcn_global_load_lds(
      (const __attribute__((address_space(1))) void*)gsrc,
      (__attribute__((address_space(3))) void*)ldst, 16, 0, 0);
}

__global__ __launch_bounds__(256, 1)
void pair_kernel(const unsigned short* __restrict__ galT,
                 const unsigned short* __restrict__ probT,
                 const float* __restrict__ fc_w,
                 float* __restrict__ Wout,
                 float* __restrict__ sPart,
                 float* __restrict__ qPart) {
  const int tid = threadIdx.x;
  const int lane = tid & 63;
  const int wid = tid >> 6;          // 0..3
  const int wr = wid >> 1;           // row half: 0/1
  const int wc = wid & 1;            // col half: 0/1
  const int q = lane >> 4;           // k-group 0..3
  const int r16 = lane & 15;
  const int swz = (lane & 7) << 4;   // row&7 == lane&7 since row bases are mult of 16

  char* ldsGal = smem;                          // 49152
  char* ldsProb = smem + TILE_BYTES;            // 2 x 49152
  float* cmax2 = (float*)(smem + 3 * TILE_BYTES);  // [2][192] by wr
  float* rmax2 = cmax2 + 2 * HW;                   // [2][192] by wc
  float* red = rmax2 + 2 * HW;                     // [8]

  const int g = blockIdx.x & 63;
  const int pc = blockIdx.x >> 6;    // 0..3 (16 probes each)

  // preload fc weights used by this thread's feat slots
  const float w0 = fc_w[tid];                         // j = tid  (<384)
  const float w1 = (tid < 128) ? fc_w[tid + 256] : 0.f;

  // stage gallery tile + probe[0]
  {
    const char* gs = (const char*)(galT + (size_t)g * HW * NC);
    for (int ch = wid; ch < 48; ch += 4)
      gl_lds16(gs + ch * 1024 + lane * 16, ldsGal + ch * 1024);
    const char* ps = (const char*)(probT + (size_t)(pc * 16) * HW * NC);
    for (int ch = wid; ch < 48; ch += 4)
      gl_lds16(ps + ch * 1024 + lane * 16, ldsProb + ch * 1024);
  }
  __syncthreads();

  float s_acc = 0.f, q_acc = 0.f;

  for (int i = 0; i < 16; ++i) {
    const int p = pc * 16 + i;
    char* cur = ldsProb + (i & 1) * TILE_BYTES;
    if (i + 1 < 16) {  // prefetch next probe tile into other buffer
      char* nxt = ldsProb + ((i + 1) & 1) * TILE_BYTES;
      const char* ps = (const char*)(probT + (size_t)(p + 1) * HW * NC);
      for (int ch = wid; ch < 48; ch += 4)
        gl_lds16(ps + ch * 1024 + lane * 16, nxt + ch * 1024);
    }

    f32x4 acc[6][6];
    #pragma unroll
    for (int m = 0; m < 6; ++m)
      #pragma unroll
      for (int n = 0; n < 6; ++n) acc[m][n] = (f32x4){0.f, 0.f, 0.f, 0.f};

    #pragma unroll
    for (int ks = 0; ks < 4; ++ks) {
      const int coff = (ks * 64 + q * 16) ^ swz;   // byte col, swizzled
      short8 a[6], b[6];
      #pragma unroll
      for (int m = 0; m < 6; ++m) {
        int row = wr * 96 + m * 16 + r16;
        a[m] = *(const short8*)(ldsGal + row * 256 + coff);
      }
      #pragma unroll
      for (int n = 0; n < 6; ++n) {
        int row = wc * 96 + n * 16 + r16;
        b[n] = *(const short8*)(cur + row * 256 + coff);
      }
      #pragma unroll
      for (int m = 0; m < 6; ++m)
        #pragma unroll
        for (int n = 0; n < 6; ++n)
          acc[m][n] = __builtin_amdgcn_mfma_f32_16x16x32_bf16(a[m], b[n], acc[m][n], 0, 0, 0);
    }

    // ---- col-max (max over rows r) : feat[0..191] indexed by s ----
    #pragma unroll
    for (int n = 0; n < 6; ++n) {
      float cm = -1e30f;
      #pragma unroll
      for (int m = 0; m < 6; ++m)
        #pragma unroll
        for (int j = 0; j < 4; ++j) cm = fmaxf(cm, acc[m][n][j]);
      cm = fmaxf(cm, __shfl_xor(cm, 16));
      cm = fmaxf(cm, __shfl_xor(cm, 32));
      if (lane < 16) cmax2[wr * HW + wc * 96 + n * 16 + r16] = cm;
    }
    // ---- row-max (max over cols s) : feat[192..383] indexed by r ----
    #pragma unroll
    for (int m = 0; m < 6; ++m) {
      #pragma unroll
      for (int j = 0; j < 4; ++j) {
        float rm = -1e30f;
        #pragma unroll
        for (int n = 0; n < 6; ++n) rm = fmaxf(rm, acc[m][n][j]);
        rm = fmaxf(rm, __shfl_xor(rm, 1));
        rm = fmaxf(rm, __shfl_xor(rm, 2));
        rm = fmaxf(rm, __shfl_xor(rm, 4));
        rm = fmaxf(rm, __shfl_xor(rm, 8));
        if (r16 == 0) rmax2[wc * HW + wr * 96 + m * 16 + q * 4 + j] = rm;
      }
    }
    __syncthreads();

    // ---- per-thread feat accumulation: thread owns j=tid (and j=tid+256) ----
    float wn;
    {
      float v0 = (tid < HW) ? fmaxf(cmax2[tid], cmax2[HW + tid])
                            : fmaxf(rmax2[tid - HW], rmax2[HW + tid - HW]);
      s_acc += v0; q_acc += v0 * v0; wn = v0 * w0;
      if (tid < 128) {
        int r = tid + 64;  // j = tid+256 -> rowmax index tid+256-192
        float v1 = fmaxf(rmax2[r], rmax2[HW + r]);
        s_acc += v1; q_acc += v1 * v1; wn += v1 * w1;
      }
    }
    // block-reduce wn -> W[n]
    #pragma unroll
    for (int msk = 1; msk < 64; msk <<= 1) wn += __shfl_xor(wn, msk);
    if (lane == 0) red[wid] = wn;
    __syncthreads();
    if (tid == 0) Wout[p * NG + g] = red[0] + red[1] + red[2] + red[3];
    __syncthreads();  // protects red/cmax2/rmax2 reuse; drains prefetch vmcnt
  }

  // block-reduce running sums -> per-block partials
  #pragma unroll
  for (int msk = 1; msk < 64; msk <<= 1) {
    s_acc += __shfl_xor(s_acc, msk);
    q_acc += __shfl_xor(q_acc, msk);
  }
  if (lane == 0) { red[wid] = s_acc; red[4 + wid] = q_acc; }
  __syncthreads();
  if (tid == 0) {
    sPart[blockIdx.x] = red[0] + red[1] + red[2] + red[3];
    qPart[blockIdx.x] = red[4] + red[5] + red[6] + red[7];
  }
}

// ---------------------------------------------------------------------------
// Finalize: exact BN -> fc -> BN chain on scalars. One block, 512 threads.
// ---------------------------------------------------------------------------
__device__ __forceinline__ float block_sum_512(float v, float* rbuf, float* bc) {
  int t = threadIdx.x, lane = t & 63, wid = t >> 6;
  #pragma unroll
  for (int m = 1; m < 64; m <<= 1) v += __shfl_xor(v, m);
  if (lane == 0) rbuf[wid] = v;
  __syncthreads();
  if (t == 0) {
    float r = 0.f;
    for (int i = 0; i < 8; ++i) r += rbuf[i];
    bc[0] = r;
  }
  __syncthreads();
  float res = bc[0];
  __syncthreads();
  return res;
}

__global__ void finalize_kernel(const float* __restrict__ Wv,
                                const float* __restrict__ sPart,
                                const float* __restrict__ qPart,
                                const float* __restrict__ fc_w,
                                const float* __restrict__ fc_b,
                                const float* __restrict__ bn_g,
                                const float* __restrict__ bn_b,
                                const float* __restrict__ lbn_g,
                                const float* __restrict__ lbn_b,
                                float* __restrict__ out) {
  __shared__ float rbuf[8];
  __shared__ float bc[1];
  const int t = threadIdx.x;  // 512

  float s_l = (t < 256) ? sPart[t] : 0.f;
  float q_l = (t < 256) ? qPart[t] : 0.f;
  float w_l = (t < 384) ? fc_w[t] : 0.f;
  float S = block_sum_512(s_l, rbuf, bc);
  float Q = block_sum_512(q_l, rbuf, bc);
  float SW = block_sum_512(w_l, rbuf, bc);

  const float Nf = 4096.0f * 384.0f;
  float mu = S / Nf;
  float var = Q / Nf - mu * mu;
  float istd = rsqrtf(var + KEPS);
  float cA = istd * bn_g[0];
  float off = bn_b[0] * SW + fc_b[0] - cA * mu * SW;

  float l[8];
  float ls = 0.f;
  #pragma unroll
  for (int i = 0; i < 8; ++i) {
    int n = t + i * 512;
    l[i] = cA * Wv[n] + off;
    ls += l[i];
  }
  float LS = block_sum_512(ls, rbuf, bc);
  float lmu = LS / 4096.0f;
  float lq = 0.f;
  #pragma unroll
  for (int i = 0; i < 8; ++i) { float d = l[i] - lmu; lq += d * d; }
  float LQ = block_sum_512(lq, rbuf, bc);
  float lvar = LQ / 4096.0f;
  float sc = lbn_g[0] * rsqrtf(lvar + KEPS);
  float lb = lbn_b[0];
  #pragma unroll
  for (int i = 0; i < 8; ++i) {
    int n = t + i * 512;
    out[n] = (l[i] - lmu) * sc + lb;
  }
}

// ---------------------------------------------------------------------------
extern "C" void kernel_launch(void* const* d_in, const int* in_sizes, int n_in,
                              void* d_out, int out_size, void* d_ws, size_t ws_size,
                              hipStream_t stream) {
  const float* prob  = (const float*)d_in[0];
  const float* gal   = (const float*)d_in[1];
  const float* bn_g  = (const float*)d_in[2];
  const float* bn_b  = (const float*)d_in[3];
  const float* fc_w  = (const float*)d_in[4];
  const float* fc_b  = (const float*)d_in[5];
  const float* lbn_g = (const float*)d_in[6];
  const float* lbn_b = (const float*)d_in[7];
  float* out = (float*)d_out;

  char* ws = (char*)d_ws;
  unsigned short* galT  = (unsigned short*)(ws);            // 3,145,728 B
  unsigned short* probT = (unsigned short*)(ws + 3145728);  // 3,145,728 B
  float* Wv    = (float*)(ws + 6291456);                    // 16384 B
  float* sPart = (float*)(ws + 6307840);                    // 1024 B
  float* qPart = (float*)(ws + 6308864);                    // 1024 B

  const int lds_bytes = 3 * TILE_BYTES + 2 * 2 * HW * 4 + 32;  // 150560
  hipFuncSetAttribute((const void*)pair_kernel,
                      hipFuncAttributeMaxDynamicSharedMemorySize, lds_bytes);

  prep_kernel<<<512, 256, 0, stream>>>(prob, gal, probT, galT);
  pair_kernel<<<256, 256, lds_bytes, stream>>>(galT, probT, fc_w, Wv, sPart, qPart);
  finalize_kernel<<<1, 512, 0, stream>>>(Wv, sPart, qPart, fc_w, fc_b,
                                         bn_g, bn_b, lbn_g, lbn_b, out);
}